// Round 3
// baseline (236.813 us; speedup 1.0000x reference)
//
#include <hip/hip_runtime.h>
#include <hip/hip_bf16.h>

// GAT layer: out = h = x @ W^T  (N=200000 x 128, fp32 in / fp32 out), then
// E=500 edges: out[dst] += 0.1 * leaky_relu(attn, 0.2) * h[src].
//
// K1 history: R0 LDS-W 16w/CU = 74.5us; R1 reg-W 8w/CU = 80us; R2 pinned
// reg-W = 75us. All three: every pipe <5% busy, HBM ~2 TB/s (33us roofline).
// Diagnosis: outstanding-bytes DUTY CYCLE. 1-deep prefetch = one 8KB burst
// per loop with long dead stretches; ~5-8 waves/CU puts avg in-flight bytes
// at/below the ~11KB/CU Little's-law line for 6.3 TB/s.
// R3 design: W back in LDS (frees 128 VGPRs; conflicts are the free 2-way
// kind), 2-deep ping-pong x prefetch (rawA/rawB, statically named), grid
// 1024 blocks = 4 blocks/CU, __launch_bounds__(256,3) -> 12-16 waves/CU.
// Every consume issues the next 8KB burst: near-continuous load stream,
// 12+ waves x 16KB in flight per CU >> requirement.
// K2/K3 unchanged (race-free two-phase edge update).

typedef __attribute__((ext_vector_type(8))) short bf16x8;   // 8 bf16 = 4 VGPRs
typedef __attribute__((ext_vector_type(4))) float f32x4;

#define W_PAD 136   // 128 + 8 bf16; 272 B row stride; 2-way bank alias = free

__device__ __forceinline__ bf16x8 pack_bf16x8(float4 v0, float4 v1) {
  union { bf16x8 v; __hip_bfloat16 h[8]; } u;
  u.h[0] = __float2bfloat16(v0.x); u.h[1] = __float2bfloat16(v0.y);
  u.h[2] = __float2bfloat16(v0.z); u.h[3] = __float2bfloat16(v0.w);
  u.h[4] = __float2bfloat16(v1.x); u.h[5] = __float2bfloat16(v1.y);
  u.h[6] = __float2bfloat16(v1.z); u.h[7] = __float2bfloat16(v1.w);
  return u.v;
}

__global__ __launch_bounds__(256, 3) void gat_gemm_kernel(
    const float* __restrict__ x,
    const float* __restrict__ W,
    float* __restrict__ out,
    int N) {
  __shared__ __hip_bfloat16 Ws[128 * W_PAD];   // 34816 B -> 4 blocks/CU by LDS

  const int t256 = threadIdx.x;

  // Stage W (128x128 fp32 = 64 KB) into LDS as bf16, float4 loads. L2/L3-hot
  // across 1024 blocks, cost amortized over 12+ tiles per block.
  #pragma unroll
  for (int it = 0; it < 16; ++it) {
    int seg = t256 + it * 256;         // 0..4095 float4 segments
    int row = seg >> 5;                // 32 segments per 128-col row
    int off = (seg & 31) * 4;
    float4 v = *reinterpret_cast<const float4*>(&W[row * 128 + off]);
    union { ushort4 u4; __hip_bfloat16 h[4]; } wpk;
    wpk.h[0] = __float2bfloat16(v.x);
    wpk.h[1] = __float2bfloat16(v.y);
    wpk.h[2] = __float2bfloat16(v.z);
    wpk.h[3] = __float2bfloat16(v.w);
    *reinterpret_cast<ushort4*>(&Ws[row * W_PAD + off]) = wpk.u4;
  }
  __syncthreads();

  const int wave = t256 >> 6;
  const int lane = t256 & 63;
  const int m = lane & 15;     // W row (= out col) in A-frag / x row in B-frag
  const int q = lane >> 4;     // quad: k-subchunk q*8, D reg row q*4+j

  const int tiles = N >> 4;              // 16-row tiles (N % 16 == 0)
  const int gs = (int)gridDim.x * 4;     // global wave count (tile stride)
  int tA = (int)blockIdx.x * 4 + wave;   // this wave's 1st tile (in rawA)
  if (tA >= tiles) return;               // wave-uniform; no barriers below

  float4 rawA[8], rawB[8];

  // Prefetch tile tA into rawA.
  {
    const float* xr = x + (long)(tA * 16 + m) * 128;
    #pragma unroll
    for (int s = 0; s < 4; ++s) {
      rawA[2 * s]     = *reinterpret_cast<const float4*>(xr + s * 32 + q * 8);
      rawA[2 * s + 1] = *reinterpret_cast<const float4*>(xr + s * 32 + q * 8 + 4);
    }
  }
  // Prefetch tile tB into rawB (2-deep).
  int tB = tA + gs;
  const bool hasB0 = tB < tiles;
  if (hasB0) {
    const float* xr = x + (long)(tB * 16 + m) * 128;
    #pragma unroll
    for (int s = 0; s < 4; ++s) {
      rawB[2 * s]     = *reinterpret_cast<const float4*>(xr + s * 32 + q * 8);
      rawB[2 * s + 1] = *reinterpret_cast<const float4*>(xr + s * 32 + q * 8 + 4);
    }
  }

  while (true) {
    // ---- consume rawA (tile tA) ----
    {
      bf16x8 afrag[4];
      #pragma unroll
      for (int s = 0; s < 4; ++s)
        afrag[s] = pack_bf16x8(rawA[2 * s], rawA[2 * s + 1]);

      const int tAn = tA + 2 * gs;              // refill rawA immediately
      if (tAn < tiles) {
        const float* xr = x + (long)(tAn * 16 + m) * 128;
        #pragma unroll
        for (int s = 0; s < 4; ++s) {
          rawA[2 * s]     = *reinterpret_cast<const float4*>(xr + s * 32 + q * 8);
          rawA[2 * s + 1] = *reinterpret_cast<const float4*>(xr + s * 32 + q * 8 + 4);
        }
      }

      f32x4 acc[8];
      #pragma unroll
      for (int nt = 0; nt < 8; ++nt) acc[nt] = (f32x4){0.f, 0.f, 0.f, 0.f};
      #pragma unroll
      for (int s = 0; s < 4; ++s) {
        #pragma unroll
        for (int nt = 0; nt < 8; ++nt) {
          bf16x8 wfrag = *reinterpret_cast<const bf16x8*>(
              &Ws[(nt * 16 + m) * W_PAD + s * 32 + q * 8]);
          acc[nt] = __builtin_amdgcn_mfma_f32_16x16x32_bf16(wfrag, afrag[s],
                                                            acc[nt], 0, 0, 0);
        }
      }
      float* orow = out + (long)(tA * 16 + m) * 128 + q * 4;
      #pragma unroll
      for (int nt = 0; nt < 8; ++nt)
        *reinterpret_cast<f32x4*>(orow + nt * 16) = acc[nt];

      tA = tAn;                                  // may be >= tiles (no reload)
    }

    if (tB >= tiles) break;                      // no B tile pending -> done

    // ---- consume rawB (tile tB) ----
    {
      bf16x8 afrag[4];
      #pragma unroll
      for (int s = 0; s < 4; ++s)
        afrag[s] = pack_bf16x8(rawB[2 * s], rawB[2 * s + 1]);

      const int tBn = tB + 2 * gs;              // refill rawB immediately
      if (tBn < tiles) {
        const float* xr = x + (long)(tBn * 16 + m) * 128;
        #pragma unroll
        for (int s = 0; s < 4; ++s) {
          rawB[2 * s]     = *reinterpret_cast<const float4*>(xr + s * 32 + q * 8);
          rawB[2 * s + 1] = *reinterpret_cast<const float4*>(xr + s * 32 + q * 8 + 4);
        }
      }

      f32x4 acc[8];
      #pragma unroll
      for (int nt = 0; nt < 8; ++nt) acc[nt] = (f32x4){0.f, 0.f, 0.f, 0.f};
      #pragma unroll
      for (int s = 0; s < 4; ++s) {
        #pragma unroll
        for (int nt = 0; nt < 8; ++nt) {
          bf16x8 wfrag = *reinterpret_cast<const bf16x8*>(
              &Ws[(nt * 16 + m) * W_PAD + s * 32 + q * 8]);
          acc[nt] = __builtin_amdgcn_mfma_f32_16x16x32_bf16(wfrag, afrag[s],
                                                            acc[nt], 0, 0, 0);
        }
      }
      float* orow = out + (long)(tB * 16 + m) * 128 + q * 4;
      #pragma unroll
      for (int nt = 0; nt < 8; ++nt)
        *reinterpret_cast<f32x4*>(orow + nt * 16) = acc[nt];

      tB = tBn;
    }

    if (tA >= tiles) break;                      // A side exhausted
  }
}

__device__ __forceinline__ int detect_i64(const int* eidx) {
  int or_odd = 0;
  #pragma unroll
  for (int k = 0; k < 16; ++k) or_odd |= eidx[2 * k + 1];
  return or_odd == 0;   // int64 little-endian: high words all zero
}

// Phase A: one block per edge. Read h rows from `out` (pure read), compute
// attn, write contribution vector 0.1*attn*h_src to ws. No races.
__global__ __launch_bounds__(128) void gat_edge_attn(
    const int* __restrict__ eidx,
    const float* __restrict__ a,       // [4, 64]
    const float* __restrict__ h,       // == out, post-GEMM
    float* __restrict__ contrib,       // [E, 128] in ws
    int E) {
  const int e = blockIdx.x;
  const int c = threadIdx.x;
  const bool is64 = detect_i64(eidx);
  const int src = is64 ? eidx[2 * e] : eidx[e];
  const int dst = is64 ? eidx[2 * (E + e)] : eidx[E + e];

  const float hs = h[(long)src * 128 + c];
  const float hd = h[(long)dst * 128 + c];

  const int head = c >> 5, d = c & 31;
  float term = a[head * 64 + d] * hs + a[head * 64 + 32 + d] * hd;
  // reduce over the 32 lanes of this head (heads occupy 32-lane halves)
  term += __shfl_xor(term, 16);
  term += __shfl_xor(term, 8);
  term += __shfl_xor(term, 4);
  term += __shfl_xor(term, 2);
  term += __shfl_xor(term, 1);
  const float attn = term >= 0.f ? term : 0.2f * term;   // leaky_relu(0.2)

  contrib[(long)e * 128 + c] = 0.1f * attn * hs;
}

// Phase B: atomic scatter-add of contributions (duplicate dst handled by HW).
__global__ __launch_bounds__(128) void gat_edge_scatter(
    const int* __restrict__ eidx,
    const float* __restrict__ contrib,
    float* __restrict__ out,
    int E) {
  const int e = blockIdx.x;
  const int c = threadIdx.x;
  const bool is64 = detect_i64(eidx);
  const int dst = is64 ? eidx[2 * (E + e)] : eidx[E + e];
  atomicAdd(&out[(long)dst * 128 + c], contrib[(long)e * 128 + c]);
}

extern "C" void kernel_launch(void* const* d_in, const int* in_sizes, int n_in,
                              void* d_out, int out_size, void* d_ws, size_t ws_size,
                              hipStream_t stream) {
  const float* x  = (const float*)d_in[0];
  const int* eidx = (const int*)d_in[1];
  const float* W  = (const float*)d_in[2];
  const float* a  = (const float*)d_in[3];
  float* out = (float*)d_out;
  float* contrib = (float*)d_ws;     // needs E*128*4 = 256 KB

  const int N = in_sizes[0] / 128;   // 200000
  const int E = in_sizes[1] / 2;     // 500

  const int tiles = N / 16;          // 12500
  int blocks = (tiles + 3) / 4;
  if (blocks > 1024) blocks = 1024;  // 4 blocks/CU, 16 waves/CU nominal
  gat_gemm_kernel<<<blocks, 256, 0, stream>>>(x, W, out, N);
  gat_edge_attn<<<E, 128, 0, stream>>>(eidx, a, out, contrib, E);
  gat_edge_scatter<<<E, 128, 0, stream>>>(eidx, contrib, out, E);
}